// Round 1
// baseline (471.169 us; speedup 1.0000x reference)
//
#include <hip/hip_runtime.h>
#include <hip/hip_bf16.h>

// ---------------------------------------------------------------------------
// YOLOv3 post-processing pipeline:
//   K1 decode  : boxes (y1,x1,y2,x2 px) + sigmoid(conf) per anchor
//   K2 topk    : per (b,class) exact top-100 of 22743 scores via 2-level
//                histogram radix select (fast-math surrogate for selection,
//                exact recompute of ~200 candidates for values/ordering)
//   K3 nms     : greedy NMS (reference-exact sequential semantics)
//   K4 final   : per-image top-100 of 8000 candidates (stable ties incl. -1.0)
// ---------------------------------------------------------------------------

#define NTOT   22743      // 3*(19^2 + 38^2 + 76^2)
#define NL1    1083       // end of layer0 region
#define NL2    5415       // end of layer1 region
#define NCLS   80
#define TOPK   100
#define SCORE_THR 0.2f
#define NMS_THR   0.3f

__device__ __forceinline__ float sig_exact(float x) {
    return 1.0f / (1.0f + expf(-x));          // precise OCML expf + IEEE div
}
__device__ __forceinline__ float sig_fast(float x) {
    // monotone surrogate, rel err ~1e-6 << 2^-9 select margin
    return __builtin_amdgcn_rcpf(1.0f + __expf(-x));
}

// class-logit gather: feats[b, a*85+5+c, y, x], flattened spatial s = y*gw+x
__device__ __forceinline__ float load_cls(const float* __restrict__ f0,
                                          const float* __restrict__ f1,
                                          const float* __restrict__ f2,
                                          int b, int c, int n) {
    const float* f; int rel, ghw;
    if (n < NL1)      { f = f0; rel = n;       ghw = 361;  }
    else if (n < NL2) { f = f1; rel = n - NL1; ghw = 1444; }
    else              { f = f2; rel = n - NL2; ghw = 5776; }
    int s = rel / 3; int a = rel - 3 * s;
    return f[(b * 255 + a * 85 + 5 + c) * ghw + s];
}

// -------------------------- K1: decode ------------------------------------
__global__ __launch_bounds__(256) void k_decode(
    const float* __restrict__ f0, const float* __restrict__ f1,
    const float* __restrict__ f2, const float* __restrict__ anchors,
    const float* __restrict__ imshape, float4* __restrict__ boxes,
    float* __restrict__ conf_sig, int total) {
    int gid = blockIdx.x * 256 + threadIdx.x;
    if (gid >= total) return;
    int b = gid / NTOT; int n = gid - b * NTOT;

    const float* f; int ghw, gw, rel, l, s, a, y, x;
    if (n < NL1)      { f=f0; rel=n;     ghw=361;  gw=19; l=0; s=rel/3; a=rel-3*s; y=s/19; x=s-y*19; }
    else if (n < NL2) { f=f1; rel=n-NL1; ghw=1444; gw=38; l=1; s=rel/3; a=rel-3*s; y=s/38; x=s-y*38; }
    else              { f=f2; rel=n-NL2; ghw=5776; gw=76; l=2; s=rel/3; a=rel-3*s; y=s/76; x=s-y*76; }

    const float* p = f + ((b * 255 + a * 85) * ghw + s);
    float tx = p[0], ty = p[ghw], tw = p[2*ghw], th = p[3*ghw], tc = p[4*ghw];

    int arow = (2 - l) * 3 + a;
    float aw = anchors[arow * 2], ah = anchors[arow * 2 + 1];
    float imh = imshape[0], imw = imshape[1];
    float gf = (float)gw;                       // gh == gw for all layers

    float bxx = (sig_exact(tx) + (float)x) / gf;   // ref: /gh
    float bxy = (sig_exact(ty) + (float)y) / gf;   // ref: /gw
    float bw  = expf(tw) * aw / 608.0f;
    float bh  = expf(th) * ah / 608.0f;

    float r  = fminf(608.0f / imh, 608.0f / imw);
    float nh = rintf(imh * r), nw = rintf(imw * r);
    float offy = (608.0f - nh) / 2.0f / 608.0f;
    float offx = (608.0f - nw) / 2.0f / 608.0f;
    float scy = 608.0f / nh, scx = 608.0f / nw;

    float cy = (bxy - offy) * scy;
    float cx = (bxx - offx) * scx;
    float hh = bh * scy, ww = bw * scx;

    boxes[gid] = make_float4((cy - hh / 2.0f) * imh, (cx - ww / 2.0f) * imw,
                             (cy + hh / 2.0f) * imh, (cx + ww / 2.0f) * imw);
    conf_sig[gid] = sig_exact(tc);
}

// ------------------ shared select helpers ---------------------------------
// p = max h with suffix_count(h) >= target; above = suffix_count(p+1)
__device__ void find_pivot(unsigned* hist, int H, unsigned target,
                           unsigned* suf, unsigned* sh_p, unsigned* sh_above) {
    const int tid = threadIdx.x;
    const int per = H >> 8;
    unsigned acc = 0;
    for (int u = 0; u < per; ++u) acc += hist[tid * per + u];
    suf[tid] = acc;
    __syncthreads();
    for (int off = 1; off < 256; off <<= 1) {
        unsigned v = (tid + off < 256) ? suf[tid + off] : 0u;
        __syncthreads();
        suf[tid] += v;
        __syncthreads();
    }
    unsigned mysuf = suf[tid];
    unsigned nxt = (tid == 255) ? 0u : suf[tid + 1];
    if (mysuf >= target && nxt < target) {
        unsigned above = nxt;
        for (int h = tid * per + per - 1; h >= tid * per; --h) {
            unsigned c2 = above + hist[h];
            if (c2 >= target) { *sh_p = (unsigned)h; *sh_above = above; break; }
            above = c2;
        }
    }
    __syncthreads();
}

__device__ void sort512(unsigned long long* buf) {   // descending bitonic
    const int tid = threadIdx.x;
    for (int k = 2; k <= 512; k <<= 1)
        for (int j = k >> 1; j > 0; j >>= 1) {
            __syncthreads();
            for (int i = tid; i < 512; i += 256) {
                int ixj = i ^ j;
                if (ixj > i) {
                    unsigned long long a = buf[i], bb = buf[ixj];
                    bool desc = ((i & k) == 0);
                    if (desc ? (a < bb) : (a > bb)) { buf[i] = bb; buf[ixj] = a; }
                }
            }
        }
    __syncthreads();
}

// -------------------------- K2: per-class top-100 -------------------------
__global__ __launch_bounds__(256) void k_topk(
    const float* __restrict__ f0, const float* __restrict__ f1,
    const float* __restrict__ f2, const float* __restrict__ conf_sig,
    const float4* __restrict__ boxes, float* __restrict__ top_s,
    float4* __restrict__ top_b) {
    __shared__ unsigned short sc16[NTOT + 1];      // 45.5 KB quantized keys
    __shared__ unsigned int   hist[2048];          // 8 KB
    __shared__ unsigned long long buf[512];        // 4 KB
    __shared__ unsigned int   suf[256];
    __shared__ unsigned int   hist2[16];
    __shared__ unsigned int   sh_p1, sh_above1, sh_qstar, sh_cnt;

    const int tid = threadIdx.x;
    const int row = blockIdx.x;
    const int b = row / NCLS, c = row - b * NCLS;
    const float* cs_base = conf_sig + b * NTOT;

    for (int i = tid; i < 2048; i += 256) hist[i] = 0;
    if (tid < 16) hist2[tid] = 0;
    if (tid == 0) sh_cnt = 0;
    __syncthreads();

    // pass 1: surrogate scores -> 16-bit keys + 11-bit histogram
    for (int n = tid; n < NTOT; n += 256) {
        float t = load_cls(f0, f1, f2, b, c, n);
        float sc = cs_base[n] * sig_fast(t);
        unsigned bits = __float_as_uint(sc);
        sc16[n] = (unsigned short)(bits >> 15);
        atomicAdd(&hist[bits >> 19], 1u);
    }
    __syncthreads();

    find_pivot(hist, 2048, TOPK, suf, &sh_p1, &sh_above1);
    unsigned p1 = sh_p1, above1 = sh_above1;

    // level 2: 16 sub-bins of the pivot bin
    for (int n = tid; n < NTOT; n += 256) {
        unsigned q = sc16[n];
        if ((q >> 4) == p1) atomicAdd(&hist2[q & 15u], 1u);
    }
    __syncthreads();
    if (tid == 0) {
        unsigned target2 = TOPK - above1, cum = 0;
        for (int v = 15; v >= 0; --v) {
            unsigned c2 = cum + hist2[v];
            if (c2 >= target2) { sh_qstar = (p1 << 4) | (unsigned)v; break; }
            cum = c2;
        }
    }
    __syncthreads();
    unsigned qsel = sh_qstar > 0 ? sh_qstar - 1 : 0;   // 2^-9 margin >> fast-math err

    // pass 3: exact recompute of candidates only
    for (int n = tid; n < NTOT; n += 256) {
        if (sc16[n] >= qsel) {
            float t = load_cls(f0, f1, f2, b, c, n);
            float sc = cs_base[n] * sig_exact(t);
            unsigned bits = __float_as_uint(sc);
            unsigned slot = atomicAdd(&sh_cnt, 1u);
            if (slot < 512)
                buf[slot] = (((unsigned long long)bits) << 32) | (unsigned)(~n);
        }
    }
    __syncthreads();
    unsigned M = sh_cnt; if (M > 512) M = 512;
    for (int i = tid; i < 512; i += 256) if ((unsigned)i >= M) buf[i] = 0ull;
    __syncthreads();
    sort512(buf);

    if (tid < TOPK) {
        unsigned long long k = buf[tid];
        unsigned bits = (unsigned)(k >> 32);
        int n = (int)(~(unsigned)k);
        top_s[row * TOPK + tid] = __uint_as_float(bits);
        top_b[row * TOPK + tid] = boxes[b * NTOT + n];
    }
}

// -------------------------- K3: greedy NMS --------------------------------
__global__ __launch_bounds__(128) void k_nms(
    const float* __restrict__ top_s, const float4* __restrict__ top_b,
    float* __restrict__ cand) {
    __shared__ float by1[TOPK], bx1[TOPK], by2[TOPK], bx2[TOPK], bar[TOPK], bs[TOPK];
    __shared__ unsigned char sup[TOPK];
    const int t = threadIdx.x, row = blockIdx.x;
    if (t < TOPK) {
        float4 bb = top_b[row * TOPK + t];
        by1[t] = bb.x; bx1[t] = bb.y; by2[t] = bb.z; bx2[t] = bb.w;
        bs[t] = top_s[row * TOPK + t];
        bar[t] = fmaxf(bb.z - bb.x, 0.0f) * fmaxf(bb.w - bb.y, 0.0f);
        sup[t] = 0;
    }
    __syncthreads();
    for (int i = 0; i < TOPK; ++i) {
        bool keep_i = (bs[i] >= SCORE_THR) && (sup[i] == 0);
        if (keep_i && t > i && t < TOPK) {
            float iy1 = fmaxf(by1[i], by1[t]);
            float ix1 = fmaxf(bx1[i], bx1[t]);
            float iy2 = fminf(by2[i], by2[t]);
            float ix2 = fminf(bx2[i], bx2[t]);
            float inter = fmaxf(iy2 - iy1, 0.0f) * fmaxf(ix2 - ix1, 0.0f);
            float iou = inter / (bar[i] + bar[t] - inter + 1e-9f);
            if (iou > NMS_THR) sup[t] = 1;
        }
        __syncthreads();
    }
    if (t < TOPK) {
        bool keep = (bs[t] >= SCORE_THR) && (sup[t] == 0);
        cand[row * TOPK + t] = keep ? bs[t] : -1.0f;
    }
}

// -------------------------- K4: per-image top-100 -------------------------
__global__ __launch_bounds__(256) void k_final(
    const float* __restrict__ cand, const float4* __restrict__ top_b,
    float* __restrict__ out) {
    __shared__ float cs[8000];                     // 32 KB
    __shared__ unsigned int hist[4096];            // 16 KB
    __shared__ unsigned long long buf[512];
    __shared__ unsigned int suf[256];
    __shared__ unsigned int sh_kp, sh_p1, sh_above1, sh_p2, sh_above2, sh_cnt;

    const int tid = threadIdx.x, b = blockIdx.x;
    if (tid == 0) { sh_kp = 0; sh_cnt = 0; }
    for (int i = tid; i < 4096; i += 256) hist[i] = 0;
    __syncthreads();

    unsigned lk = 0;
    for (int i = tid; i < 8000; i += 256) {
        float v = cand[b * 8000 + i];
        cs[i] = v;
        if (v > -0.5f) lk++;
    }
    atomicAdd(&sh_kp, lk);
    __syncthreads();
    unsigned Kp = sh_kp;

    if (Kp >= TOPK) {
        for (int i = tid; i < 8000; i += 256)
            if (cs[i] > -0.5f) atomicAdd(&hist[__float_as_uint(cs[i]) >> 19], 1u);
        __syncthreads();
        find_pivot(hist, 2048, TOPK, suf, &sh_p1, &sh_above1);
        unsigned p1 = sh_p1, above1 = sh_above1;
        for (int i = tid; i < 4096; i += 256) hist[i] = 0;
        __syncthreads();
        for (int i = tid; i < 8000; i += 256) {
            float v = cs[i];
            if (v > -0.5f) {
                unsigned bits = __float_as_uint(v);
                if ((bits >> 19) == p1) atomicAdd(&hist[(bits >> 7) & 0xFFFu], 1u);
            }
        }
        __syncthreads();
        find_pivot(hist, 4096, TOPK - above1, suf, &sh_p2, &sh_above2);
        unsigned p2 = sh_p2;
        for (int i = tid; i < 8000; i += 256) {
            float v = cs[i];
            if (v > -0.5f) {
                unsigned bits = __float_as_uint(v);
                unsigned b1 = bits >> 19;
                if (b1 > p1 || (b1 == p1 && ((bits >> 7) & 0xFFFu) >= p2)) {
                    unsigned slot = atomicAdd(&sh_cnt, 1u);
                    if (slot < 512)
                        buf[slot] = (((unsigned long long)bits) << 32) | (unsigned)(~i);
                }
            }
        }
        __syncthreads();
        unsigned M = sh_cnt; if (M > 512) M = 512;
        for (int i = tid; i < 512; i += 256) if ((unsigned)i >= M) buf[i] = 0ull;
    } else {
        // < 100 kept: all kept + smallest flat indices among exact -1.0 ties
        for (int i = tid; i < 512; i += 256) buf[i] = 0ull;
        __syncthreads();
        for (int i = tid; i < 8000; i += 256) {
            float v = cs[i];
            if (v > -0.5f) {
                unsigned slot = atomicAdd(&sh_cnt, 1u);
                buf[slot] = (((unsigned long long)__float_as_uint(v)) << 32) | (unsigned)(~i);
            }
        }
        __syncthreads();
        if (tid == 0) {
            unsigned need = TOPK - Kp, got = 0;
            for (int i = 0; i < 8000 && got < need; ++i)
                if (cs[i] <= -0.5f) { buf[Kp + got] = (unsigned)(~i); got++; }
        }
    }
    __syncthreads();
    sort512(buf);

    if (tid < TOPK) {
        unsigned long long k = buf[tid];
        int i = (int)(~(unsigned)k);
        int c = i / TOPK; int kk = i - c * TOPK;
        float4 bb = top_b[(b * NCLS + c) * TOPK + kk];
        int base = (b * TOPK + tid) * 6;
        out[base + 0] = bb.x; out[base + 1] = bb.y;
        out[base + 2] = bb.z; out[base + 3] = bb.w;
        out[base + 4] = cs[i]; out[base + 5] = (float)c;
    }
}

// ---------------------------------------------------------------------------
extern "C" void kernel_launch(void* const* d_in, const int* in_sizes, int n_in,
                              void* d_out, int out_size, void* d_ws, size_t ws_size,
                              hipStream_t stream) {
    (void)n_in; (void)out_size; (void)ws_size;
    const float* f0      = (const float*)d_in[0];
    const float* f1      = (const float*)d_in[1];
    const float* f2      = (const float*)d_in[2];
    const float* anchors = (const float*)d_in[3];
    const float* imshape = (const float*)d_in[4];
    const int B = in_sizes[0] / (255 * 19 * 19);

    char* ws = (char*)d_ws;
    size_t o = 0;
    float4* boxes    = (float4*)(ws + o); o += (size_t)B * NTOT * sizeof(float4);
    float*  conf_sig = (float*)(ws + o);  o += (size_t)B * NTOT * sizeof(float);
    float*  top_s    = (float*)(ws + o);  o += (size_t)B * NCLS * TOPK * sizeof(float);
    float4* top_b    = (float4*)(ws + o); o += (size_t)B * NCLS * TOPK * sizeof(float4);
    float*  cand     = (float*)(ws + o);  o += (size_t)B * NCLS * TOPK * sizeof(float);
    float*  out      = (float*)d_out;

    const int total = B * NTOT;
    k_decode<<<(total + 255) / 256, 256, 0, stream>>>(f0, f1, f2, anchors, imshape,
                                                      boxes, conf_sig, total);
    k_topk<<<B * NCLS, 256, 0, stream>>>(f0, f1, f2, conf_sig, boxes, top_s, top_b);
    k_nms<<<B * NCLS, 128, 0, stream>>>(top_s, top_b, cand);
    k_final<<<B, 256, 0, stream>>>(cand, top_b, out);
}

// Round 2
// 406.284 us; speedup vs baseline: 1.1597x; 1.1597x over previous
//
#include <hip/hip_runtime.h>
#include <hip/hip_bf16.h>

// ---------------------------------------------------------------------------
// YOLOv3 post-processing pipeline (round 2):
//   K1 decode : boxes + exact sigmoid(conf) written PLANAR (b,l,a,s) so the
//               top-k kernel reads it coalesced
//   K2 topk   : per (b,class) exact top-100 via single-level 8192-bin radix
//               select; planar coalesced reads; no LDS key staging
//               (37.9 KB LDS -> 4 blocks/CU vs 2 before)
//   K3 nms    : greedy NMS, one wave per row, shuffle broadcast, NO barriers
//   K4 final  : per-image top-100 of 8000 (unchanged, was exact)
// ---------------------------------------------------------------------------

#define NTOT   22743      // 3*(19^2 + 38^2 + 76^2)
#define NCLS   80
#define TOPK   100
#define SCORE_THR 0.2f
#define NMS_THR   0.3f

__device__ __forceinline__ float sig_exact(float x) {
    return 1.0f / (1.0f + expf(-x));          // precise OCML expf + IEEE div
}
__device__ __forceinline__ float sig_fast(float x) {
    // monotone surrogate, rel err ~1e-6 << 2^-6 bin margin
    return __builtin_amdgcn_rcpf(1.0f + __expf(-x));
}

// -------------------------- K1: decode ------------------------------------
__global__ __launch_bounds__(256) void k_decode(
    const float* __restrict__ f0, const float* __restrict__ f1,
    const float* __restrict__ f2, const float* __restrict__ anchors,
    const float* __restrict__ imshape, float4* __restrict__ boxes,
    float* __restrict__ conf_p, int total) {
    int gid = blockIdx.x * 256 + threadIdx.x;
    if (gid >= total) return;
    int b = gid / NTOT; int n = gid - b * NTOT;

    const float* f; int ghw, gw, rel, l, s, a, y, x, off;
    if (n < 1083)      { f=f0; rel=n;      ghw=361;  gw=19; l=0; off=0;    s=rel/3; a=rel-3*s; y=s/19; x=s-y*19; }
    else if (n < 5415) { f=f1; rel=n-1083; ghw=1444; gw=38; l=1; off=1083; s=rel/3; a=rel-3*s; y=s/38; x=s-y*38; }
    else               { f=f2; rel=n-5415; ghw=5776; gw=76; l=2; off=5415; s=rel/3; a=rel-3*s; y=s/76; x=s-y*76; }

    const float* p = f + ((size_t)(b * 255 + a * 85) * ghw + s);
    float tx = p[0], ty = p[ghw], tw = p[2*ghw], th = p[3*ghw], tc = p[4*ghw];

    int arow = (2 - l) * 3 + a;
    float aw = anchors[arow * 2], ah = anchors[arow * 2 + 1];
    float imh = imshape[0], imw = imshape[1];
    float gf = (float)gw;                       // gh == gw for all layers

    float bxx = (sig_exact(tx) + (float)x) / gf;
    float bxy = (sig_exact(ty) + (float)y) / gf;
    float bw  = expf(tw) * aw / 608.0f;
    float bh  = expf(th) * ah / 608.0f;

    float r  = fminf(608.0f / imh, 608.0f / imw);
    float nh = rintf(imh * r), nw = rintf(imw * r);
    float offy = (608.0f - nh) / 2.0f / 608.0f;
    float offx = (608.0f - nw) / 2.0f / 608.0f;
    float scy = 608.0f / nh, scx = 608.0f / nw;

    float cy = (bxy - offy) * scy;
    float cx = (bxx - offx) * scx;
    float hh = bh * scy, ww = bw * scx;

    boxes[gid] = make_float4((cy - hh / 2.0f) * imh, (cx - ww / 2.0f) * imw,
                             (cy + hh / 2.0f) * imh, (cx + ww / 2.0f) * imw);
    // planar: conf_p[b][off + a*ghw + s]
    conf_p[(size_t)b * NTOT + off + a * ghw + s] = sig_exact(tc);
}

// ------------------ shared select helpers ---------------------------------
// p = max h with suffix_count(h) >= target; above = suffix_count(p+1)
__device__ void find_pivot(unsigned* hist, int H, unsigned target,
                           unsigned* suf, unsigned* sh_p, unsigned* sh_above) {
    const int tid = threadIdx.x;
    const int per = H >> 8;
    unsigned acc = 0;
    for (int u = 0; u < per; ++u) acc += hist[tid * per + u];
    suf[tid] = acc;
    __syncthreads();
    for (int off = 1; off < 256; off <<= 1) {
        unsigned v = (tid + off < 256) ? suf[tid + off] : 0u;
        __syncthreads();
        suf[tid] += v;
        __syncthreads();
    }
    unsigned mysuf = suf[tid];
    unsigned nxt = (tid == 255) ? 0u : suf[tid + 1];
    if (mysuf >= target && nxt < target) {
        unsigned above = nxt;
        for (int h = tid * per + per - 1; h >= tid * per; --h) {
            unsigned c2 = above + hist[h];
            if (c2 >= target) { *sh_p = (unsigned)h; *sh_above = above; break; }
            above = c2;
        }
    }
    __syncthreads();
}

__device__ void sort512(unsigned long long* buf) {   // descending bitonic
    const int tid = threadIdx.x;
    for (int k = 2; k <= 512; k <<= 1)
        for (int j = k >> 1; j > 0; j >>= 1) {
            __syncthreads();
            for (int i = tid; i < 512; i += 256) {
                int ixj = i ^ j;
                if (ixj > i) {
                    unsigned long long a = buf[i], bb = buf[ixj];
                    bool desc = ((i & k) == 0);
                    if (desc ? (a < bb) : (a > bb)) { buf[i] = bb; buf[ixj] = a; }
                }
            }
        }
    __syncthreads();
}

// -------------------------- K2: per-class top-100 -------------------------
__global__ __launch_bounds__(256) void k_topk(
    const float* __restrict__ f0, const float* __restrict__ f1,
    const float* __restrict__ f2, const float* __restrict__ conf_p,
    const float4* __restrict__ boxes, float* __restrict__ top_s,
    float4* __restrict__ top_b) {
    __shared__ unsigned int hist[8192];            // 32 KB
    __shared__ unsigned long long buf[512];        // 4 KB
    __shared__ unsigned int suf[256];              // 1 KB
    __shared__ unsigned int sh_p, sh_above, sh_cnt;

    const int tid = threadIdx.x;
    const int row = blockIdx.x;
    const int b = row / NCLS, c = row - b * NCLS;

    for (int i = tid; i < 8192; i += 256) hist[i] = 0;
    if (tid == 0) sh_cnt = 0;
    __syncthreads();

    const float* fs[3]  = {f0, f1, f2};
    const int ghws[3]   = {361, 1444, 5776};
    const int offs[3]   = {0, 1083, 5415};

    // pass 1: coalesced planar scan -> 8192-bin histogram of surrogate bits
    for (int l = 0; l < 3; ++l) {
        const int ghw = ghws[l];
        for (int a = 0; a < 3; ++a) {
            const float* cp = fs[l] + (size_t)(b * 255 + a * 85 + 5 + c) * ghw;
            const float* cf = conf_p + (size_t)b * NTOT + offs[l] + a * ghw;
            for (int s = tid; s < ghw; s += 256) {
                float sc = cf[s] * sig_fast(cp[s]);
                atomicAdd(&hist[__float_as_uint(sc) >> 17], 1u);
            }
        }
    }
    __syncthreads();

    find_pivot(hist, 8192, TOPK, suf, &sh_p, &sh_above);
    const unsigned bthr = sh_p > 0 ? ((sh_p - 1) << 17) : 0u;  // one-bin margin

    // pass 2: recompute surrogate; exact-recompute candidates only
    for (int l = 0; l < 3; ++l) {
        const int ghw = ghws[l];
        for (int a = 0; a < 3; ++a) {
            const float* cp = fs[l] + (size_t)(b * 255 + a * 85 + 5 + c) * ghw;
            const float* cf = conf_p + (size_t)b * NTOT + offs[l] + a * ghw;
            for (int s = tid; s < ghw; s += 256) {
                float cfv = cf[s], t = cp[s];
                float scf = cfv * sig_fast(t);
                if (__float_as_uint(scf) >= bthr) {
                    float sce = cfv * sig_exact(t);
                    int n = offs[l] + 3 * s + a;
                    unsigned slot = atomicAdd(&sh_cnt, 1u);
                    if (slot < 512)
                        buf[slot] = (((unsigned long long)__float_as_uint(sce)) << 32)
                                    | (unsigned)(~n);
                }
            }
        }
    }
    __syncthreads();
    unsigned M = sh_cnt; if (M > 512) M = 512;
    for (int i = tid; i < 512; i += 256) if ((unsigned)i >= M) buf[i] = 0ull;
    __syncthreads();
    sort512(buf);

    if (tid < TOPK) {
        unsigned long long k = buf[tid];
        unsigned bits = (unsigned)(k >> 32);
        int n = (int)(~(unsigned)k);
        top_s[row * TOPK + tid] = __uint_as_float(bits);
        top_b[row * TOPK + tid] = boxes[(size_t)b * NTOT + n];
    }
}

// -------------------------- K3: greedy NMS (wave per row) -----------------
__global__ __launch_bounds__(256) void k_nms(
    const float* __restrict__ top_s, const float4* __restrict__ top_b,
    float* __restrict__ cand) {
    const int lane = threadIdx.x & 63;
    const int row  = blockIdx.x * 4 + (threadIdx.x >> 6);
    const float4* bb = top_b + (size_t)row * TOPK;
    const float*  ss = top_s + (size_t)row * TOPK;

    const int j0 = lane, j1 = lane + 64;
    const bool v1 = (j1 < TOPK);
    float4 B0 = bb[j0];
    float  s0 = ss[j0];
    float4 B1 = v1 ? bb[j1] : make_float4(0.f, 0.f, 0.f, 0.f);
    float  s1 = v1 ? ss[j1] : -1.0f;
    float ar0 = fmaxf(B0.z - B0.x, 0.f) * fmaxf(B0.w - B0.y, 0.f);
    float ar1 = fmaxf(B1.z - B1.x, 0.f) * fmaxf(B1.w - B1.y, 0.f);
    int sup0 = 0, sup1 = 0;

    for (int i = 0; i < TOPK; ++i) {
        const int src = i & 63;
        const bool hi = (i >= 64);
        float yi1 = __shfl(hi ? B1.x : B0.x, src, 64);
        float xi1 = __shfl(hi ? B1.y : B0.y, src, 64);
        float yi2 = __shfl(hi ? B1.z : B0.z, src, 64);
        float xi2 = __shfl(hi ? B1.w : B0.w, src, 64);
        float si  = __shfl(hi ? s1   : s0,   src, 64);
        int  supi = __shfl(hi ? sup1 : sup0, src, 64);
        bool keep_i = (si >= SCORE_THR) && (supi == 0);
        if (keep_i) {
            float ari = fmaxf(yi2 - yi1, 0.f) * fmaxf(xi2 - xi1, 0.f);
            if (j0 > i) {
                float ty1 = fmaxf(yi1, B0.x), tx1 = fmaxf(xi1, B0.y);
                float ty2 = fminf(yi2, B0.z), tx2 = fminf(xi2, B0.w);
                float inter = fmaxf(ty2 - ty1, 0.f) * fmaxf(tx2 - tx1, 0.f);
                float iou = inter / (ari + ar0 - inter + 1e-9f);
                if (iou > NMS_THR) sup0 = 1;
            }
            if (v1 && j1 > i) {
                float ty1 = fmaxf(yi1, B1.x), tx1 = fmaxf(xi1, B1.y);
                float ty2 = fminf(yi2, B1.z), tx2 = fminf(xi2, B1.w);
                float inter = fmaxf(ty2 - ty1, 0.f) * fmaxf(tx2 - tx1, 0.f);
                float iou = inter / (ari + ar1 - inter + 1e-9f);
                if (iou > NMS_THR) sup1 = 1;
            }
        }
    }
    cand[(size_t)row * TOPK + j0] = (s0 >= SCORE_THR && sup0 == 0) ? s0 : -1.0f;
    if (v1)
        cand[(size_t)row * TOPK + j1] = (s1 >= SCORE_THR && sup1 == 0) ? s1 : -1.0f;
}

// -------------------------- K4: per-image top-100 -------------------------
__global__ __launch_bounds__(256) void k_final(
    const float* __restrict__ cand, const float4* __restrict__ top_b,
    float* __restrict__ out) {
    __shared__ float cs[8000];                     // 32 KB
    __shared__ unsigned int hist[4096];            // 16 KB
    __shared__ unsigned long long buf[512];
    __shared__ unsigned int suf[256];
    __shared__ unsigned int sh_kp, sh_p1, sh_above1, sh_p2, sh_above2, sh_cnt;

    const int tid = threadIdx.x, b = blockIdx.x;
    if (tid == 0) { sh_kp = 0; sh_cnt = 0; }
    for (int i = tid; i < 4096; i += 256) hist[i] = 0;
    __syncthreads();

    unsigned lk = 0;
    for (int i = tid; i < 8000; i += 256) {
        float v = cand[b * 8000 + i];
        cs[i] = v;
        if (v > -0.5f) lk++;
    }
    atomicAdd(&sh_kp, lk);
    __syncthreads();
    unsigned Kp = sh_kp;

    if (Kp >= TOPK) {
        for (int i = tid; i < 8000; i += 256)
            if (cs[i] > -0.5f) atomicAdd(&hist[__float_as_uint(cs[i]) >> 19], 1u);
        __syncthreads();
        find_pivot(hist, 2048, TOPK, suf, &sh_p1, &sh_above1);
        unsigned p1 = sh_p1, above1 = sh_above1;
        for (int i = tid; i < 4096; i += 256) hist[i] = 0;
        __syncthreads();
        for (int i = tid; i < 8000; i += 256) {
            float v = cs[i];
            if (v > -0.5f) {
                unsigned bits = __float_as_uint(v);
                if ((bits >> 19) == p1) atomicAdd(&hist[(bits >> 7) & 0xFFFu], 1u);
            }
        }
        __syncthreads();
        find_pivot(hist, 4096, TOPK - above1, suf, &sh_p2, &sh_above2);
        unsigned p2 = sh_p2;
        for (int i = tid; i < 8000; i += 256) {
            float v = cs[i];
            if (v > -0.5f) {
                unsigned bits = __float_as_uint(v);
                unsigned b1 = bits >> 19;
                if (b1 > p1 || (b1 == p1 && ((bits >> 7) & 0xFFFu) >= p2)) {
                    unsigned slot = atomicAdd(&sh_cnt, 1u);
                    if (slot < 512)
                        buf[slot] = (((unsigned long long)bits) << 32) | (unsigned)(~i);
                }
            }
        }
        __syncthreads();
        unsigned M = sh_cnt; if (M > 512) M = 512;
        for (int i = tid; i < 512; i += 256) if ((unsigned)i >= M) buf[i] = 0ull;
    } else {
        // < 100 kept: all kept + smallest flat indices among exact -1.0 ties
        for (int i = tid; i < 512; i += 256) buf[i] = 0ull;
        __syncthreads();
        for (int i = tid; i < 8000; i += 256) {
            float v = cs[i];
            if (v > -0.5f) {
                unsigned slot = atomicAdd(&sh_cnt, 1u);
                buf[slot] = (((unsigned long long)__float_as_uint(v)) << 32) | (unsigned)(~i);
            }
        }
        __syncthreads();
        if (tid == 0) {
            unsigned need = TOPK - Kp, got = 0;
            for (int i = 0; i < 8000 && got < need; ++i)
                if (cs[i] <= -0.5f) { buf[Kp + got] = (unsigned)(~i); got++; }
        }
    }
    __syncthreads();
    sort512(buf);

    if (tid < TOPK) {
        unsigned long long k = buf[tid];
        int i = (int)(~(unsigned)k);
        int c = i / TOPK; int kk = i - c * TOPK;
        float4 bb = top_b[((size_t)b * NCLS + c) * TOPK + kk];
        int base = (b * TOPK + tid) * 6;
        out[base + 0] = bb.x; out[base + 1] = bb.y;
        out[base + 2] = bb.z; out[base + 3] = bb.w;
        out[base + 4] = cs[i]; out[base + 5] = (float)c;
    }
}

// ---------------------------------------------------------------------------
extern "C" void kernel_launch(void* const* d_in, const int* in_sizes, int n_in,
                              void* d_out, int out_size, void* d_ws, size_t ws_size,
                              hipStream_t stream) {
    (void)n_in; (void)out_size; (void)ws_size;
    const float* f0      = (const float*)d_in[0];
    const float* f1      = (const float*)d_in[1];
    const float* f2      = (const float*)d_in[2];
    const float* anchors = (const float*)d_in[3];
    const float* imshape = (const float*)d_in[4];
    const int B = in_sizes[0] / (255 * 19 * 19);

    char* ws = (char*)d_ws;
    size_t o = 0;
    float4* boxes  = (float4*)(ws + o); o += (size_t)B * NTOT * sizeof(float4);
    float*  conf_p = (float*)(ws + o);  o += (size_t)B * NTOT * sizeof(float);
    float*  top_s  = (float*)(ws + o);  o += (size_t)B * NCLS * TOPK * sizeof(float);
    float4* top_b  = (float4*)(ws + o); o += (size_t)B * NCLS * TOPK * sizeof(float4);
    float*  cand   = (float*)(ws + o);  o += (size_t)B * NCLS * TOPK * sizeof(float);
    float*  out    = (float*)d_out;

    const int total = B * NTOT;
    k_decode<<<(total + 255) / 256, 256, 0, stream>>>(f0, f1, f2, anchors, imshape,
                                                      boxes, conf_p, total);
    k_topk<<<B * NCLS, 256, 0, stream>>>(f0, f1, f2, conf_p, boxes, top_s, top_b);
    k_nms<<<(B * NCLS) / 4, 256, 0, stream>>>(top_s, top_b, cand);
    k_final<<<B, 256, 0, stream>>>(cand, top_b, out);
}

// Round 3
// 340.241 us; speedup vs baseline: 1.3848x; 1.1941x over previous
//
#include <hip/hip_runtime.h>
#include <hip/hip_bf16.h>

// ---------------------------------------------------------------------------
// YOLOv3 post-processing pipeline (round 3):
//   K1 decode : boxes + exact sigmoid(conf), conf planar (b,l,a,s)
//   K2 score  : NEW — throughput kernel: all 29.1M surrogate scores as u16
//               keys into transposed keybuf[b][c][p] (coalesced both sides,
//               80 independent iters/thread -> BW-bound, not latency-bound)
//   K3 topk   : per (b,c) row: 8-keys-per-16B vector hist (12 iters vs 178),
//               pivot, collect+exact-rescore ~<=512 candidates, sort
//   K4 nms    : greedy NMS, one wave per row, shuffle broadcast
//   K5 final  : per-image top-100 of 8000
// ---------------------------------------------------------------------------

#define NTOT   22743      // 3*(19^2 + 38^2 + 76^2)
#define NCLS   80
#define TOPK   100
#define KPAD   22752      // row stride for keybuf (16B aligned, 8-div)
#define NVEC   2842       // 22736/8 full uint4 groups per row
#define SCORE_THR 0.2f
#define NMS_THR   0.3f

__device__ __forceinline__ float sig_exact(float x) {
    return 1.0f / (1.0f + expf(-x));          // precise OCML expf + IEEE div
}
__device__ __forceinline__ float sig_fast(float x) {
    // monotone surrogate, rel err ~1e-6 << 2^-6 bin margin
    return __builtin_amdgcn_rcpf(1.0f + __expf(-x));
}

// -------------------------- K1: decode ------------------------------------
__global__ __launch_bounds__(256) void k_decode(
    const float* __restrict__ f0, const float* __restrict__ f1,
    const float* __restrict__ f2, const float* __restrict__ anchors,
    const float* __restrict__ imshape, float4* __restrict__ boxes,
    float* __restrict__ conf_p, int total) {
    int gid = blockIdx.x * 256 + threadIdx.x;
    if (gid >= total) return;
    int b = gid / NTOT; int n = gid - b * NTOT;

    const float* f; int ghw, gw, rel, l, s, a, y, x, off;
    if (n < 1083)      { f=f0; rel=n;      ghw=361;  gw=19; l=0; off=0;    s=rel/3; a=rel-3*s; y=s/19; x=s-y*19; }
    else if (n < 5415) { f=f1; rel=n-1083; ghw=1444; gw=38; l=1; off=1083; s=rel/3; a=rel-3*s; y=s/38; x=s-y*38; }
    else               { f=f2; rel=n-5415; ghw=5776; gw=76; l=2; off=5415; s=rel/3; a=rel-3*s; y=s/76; x=s-y*76; }

    const float* p = f + ((size_t)(b * 255 + a * 85) * ghw + s);
    float tx = p[0], ty = p[ghw], tw = p[2*ghw], th = p[3*ghw], tc = p[4*ghw];

    int arow = (2 - l) * 3 + a;
    float aw = anchors[arow * 2], ah = anchors[arow * 2 + 1];
    float imh = imshape[0], imw = imshape[1];
    float gf = (float)gw;                       // gh == gw for all layers

    float bxx = (sig_exact(tx) + (float)x) / gf;
    float bxy = (sig_exact(ty) + (float)y) / gf;
    float bw  = expf(tw) * aw / 608.0f;
    float bh  = expf(th) * ah / 608.0f;

    float r  = fminf(608.0f / imh, 608.0f / imw);
    float nh = rintf(imh * r), nw = rintf(imw * r);
    float offy = (608.0f - nh) / 2.0f / 608.0f;
    float offx = (608.0f - nw) / 2.0f / 608.0f;
    float scy = 608.0f / nh, scx = 608.0f / nw;

    float cy = (bxy - offy) * scy;
    float cx = (bxx - offx) * scx;
    float hh = bh * scy, ww = bw * scx;

    boxes[gid] = make_float4((cy - hh / 2.0f) * imh, (cx - ww / 2.0f) * imw,
                             (cy + hh / 2.0f) * imh, (cx + ww / 2.0f) * imw);
    conf_p[(size_t)b * NTOT + off + a * ghw + s] = sig_exact(tc);
}

// -------------------------- K2: score (surrogate keys) --------------------
// grid = B * 93; chunk id -> (l, a, s-chunk). Each thread: 80 independent
// coalesced load->key->store iterations (deep MLP, BW-bound).
__global__ __launch_bounds__(256) void k_score(
    const float* __restrict__ f0, const float* __restrict__ f1,
    const float* __restrict__ f2, const float* __restrict__ conf_p,
    unsigned short* __restrict__ keybuf) {
    const int cid = blockIdx.x % 93;
    const int b   = blockIdx.x / 93;
    int l, a, ch;
    if (cid < 6)       { l = 0; a = cid >> 1;          ch = cid & 1;  }
    else if (cid < 24) { int t = cid - 6;  l = 1; a = t / 6;  ch = t - 6 * a;  }
    else               { int t = cid - 24; l = 2; a = t / 23; ch = t - 23 * a; }
    const int   ghw  = (l == 0) ? 361 : (l == 1) ? 1444 : 5776;
    const int   offs = (l == 0) ? 0   : (l == 1) ? 1083 : 5415;
    const float* f   = (l == 0) ? f0  : (l == 1) ? f1   : f2;

    const int s = ch * 256 + threadIdx.x;
    if (s >= ghw) return;
    const int p = offs + a * ghw + s;
    const float cf = conf_p[(size_t)b * NTOT + p];
    const float* cp = f + ((size_t)(b * 255 + a * 85 + 5) * ghw + s);
    unsigned short* kb = keybuf + (size_t)b * NCLS * KPAD + p;

    #pragma unroll 8
    for (int c = 0; c < NCLS; ++c) {
        float sc = cf * sig_fast(cp[(size_t)c * ghw]);
        kb[(size_t)c * KPAD] = (unsigned short)(__float_as_uint(sc) >> 16);
    }
}

// ------------------ shared select helpers ---------------------------------
__device__ void find_pivot(unsigned* hist, int H, unsigned target,
                           unsigned* suf, unsigned* sh_p, unsigned* sh_above) {
    const int tid = threadIdx.x;
    const int per = H >> 8;
    unsigned acc = 0;
    for (int u = 0; u < per; ++u) acc += hist[tid * per + u];
    suf[tid] = acc;
    __syncthreads();
    for (int off = 1; off < 256; off <<= 1) {
        unsigned v = (tid + off < 256) ? suf[tid + off] : 0u;
        __syncthreads();
        suf[tid] += v;
        __syncthreads();
    }
    unsigned mysuf = suf[tid];
    unsigned nxt = (tid == 255) ? 0u : suf[tid + 1];
    if (mysuf >= target && nxt < target) {
        unsigned above = nxt;
        for (int h = tid * per + per - 1; h >= tid * per; --h) {
            unsigned c2 = above + hist[h];
            if (c2 >= target) { *sh_p = (unsigned)h; *sh_above = above; break; }
            above = c2;
        }
    }
    __syncthreads();
}

__device__ void sort512(unsigned long long* buf) {   // descending bitonic
    const int tid = threadIdx.x;
    for (int k = 2; k <= 512; k <<= 1)
        for (int j = k >> 1; j > 0; j >>= 1) {
            __syncthreads();
            for (int i = tid; i < 512; i += 256) {
                int ixj = i ^ j;
                if (ixj > i) {
                    unsigned long long a = buf[i], bb = buf[ixj];
                    bool desc = ((i & k) == 0);
                    if (desc ? (a < bb) : (a > bb)) { buf[i] = bb; buf[ixj] = a; }
                }
            }
        }
    __syncthreads();
}

// -------------------------- K3: per-class top-100 -------------------------
__device__ __forceinline__ void collect_cand(
    int b, int c, int p, const float* __restrict__ f0,
    const float* __restrict__ f1, const float* __restrict__ f2,
    const float* __restrict__ conf_p, unsigned long long* buf,
    unsigned* sh_cnt) {
    int l, a, s, offs, ghw;
    const float* f;
    if (p < 1083)      { l = 0; offs = 0;    ghw = 361;  f = f0; }
    else if (p < 5415) { l = 1; offs = 1083; ghw = 1444; f = f1; }
    else               { l = 2; offs = 5415; ghw = 5776; f = f2; }
    int rel = p - offs;
    if (l == 0)      { a = rel / 361;  s = rel - a * 361;  }
    else if (l == 1) { a = rel / 1444; s = rel - a * 1444; }
    else             { a = rel / 5776; s = rel - a * 5776; }
    float t  = f[((size_t)(b * 255 + a * 85 + 5 + c)) * ghw + s];
    float cf = conf_p[(size_t)b * NTOT + p];
    float sce = cf * sig_exact(t);
    int n = offs + 3 * s + a;
    unsigned slot = atomicAdd(sh_cnt, 1u);
    if (slot < 512)
        buf[slot] = (((unsigned long long)__float_as_uint(sce)) << 32)
                    | (unsigned)(~n);
}

__global__ __launch_bounds__(256) void k_topk(
    const float* __restrict__ f0, const float* __restrict__ f1,
    const float* __restrict__ f2, const float* __restrict__ conf_p,
    const unsigned short* __restrict__ keybuf,
    const float4* __restrict__ boxes, float* __restrict__ top_s,
    float4* __restrict__ top_b) {
    __shared__ unsigned int hist[8192];            // 32 KB
    __shared__ unsigned long long buf[512];        // 4 KB
    __shared__ unsigned int suf[256];              // 1 KB
    __shared__ unsigned int sh_p, sh_above, sh_cnt;

    const int tid = threadIdx.x;
    const int row = blockIdx.x;
    const int b = row / NCLS, c = row - b * NCLS;
    const unsigned short* kr = keybuf + (size_t)row * KPAD;
    const uint4* kv = (const uint4*)kr;            // 8 keys per load

    for (int i = tid; i < 8192; i += 256) hist[i] = 0;
    if (tid == 0) sh_cnt = 0;
    __syncthreads();

    // pass 1: histogram of key>>1 (== float bits>>17, proven margin)
    for (int g = tid; g < NVEC; g += 256) {
        uint4 v = kv[g];
        atomicAdd(&hist[(v.x & 0xFFFFu) >> 1], 1u);
        atomicAdd(&hist[(v.x >> 16)     >> 1], 1u);
        atomicAdd(&hist[(v.y & 0xFFFFu) >> 1], 1u);
        atomicAdd(&hist[(v.y >> 16)     >> 1], 1u);
        atomicAdd(&hist[(v.z & 0xFFFFu) >> 1], 1u);
        atomicAdd(&hist[(v.z >> 16)     >> 1], 1u);
        atomicAdd(&hist[(v.w & 0xFFFFu) >> 1], 1u);
        atomicAdd(&hist[(v.w >> 16)     >> 1], 1u);
    }
    if (tid < NTOT - NVEC * 8) {                   // 7-key tail
        unsigned k = kr[NVEC * 8 + tid];
        atomicAdd(&hist[k >> 1], 1u);
    }
    __syncthreads();

    find_pivot(hist, 8192, TOPK, suf, &sh_p, &sh_above);
    const unsigned kthr = sh_p > 0 ? ((sh_p - 1) << 1) : 0u;  // one-bin margin

    // pass 2: collect candidates (keys L2-hot), exact rescore
    for (int g = tid; g < NVEC; g += 256) {
        uint4 v = kv[g];
        unsigned ks[8] = { v.x & 0xFFFFu, v.x >> 16, v.y & 0xFFFFu, v.y >> 16,
                           v.z & 0xFFFFu, v.z >> 16, v.w & 0xFFFFu, v.w >> 16 };
        #pragma unroll
        for (int j = 0; j < 8; ++j)
            if (ks[j] >= kthr)
                collect_cand(b, c, g * 8 + j, f0, f1, f2, conf_p, buf, &sh_cnt);
    }
    if (tid < NTOT - NVEC * 8) {
        int p = NVEC * 8 + tid;
        if ((unsigned)kr[p] >= kthr)
            collect_cand(b, c, p, f0, f1, f2, conf_p, buf, &sh_cnt);
    }
    __syncthreads();
    unsigned M = sh_cnt; if (M > 512) M = 512;
    for (int i = tid; i < 512; i += 256) if ((unsigned)i >= M) buf[i] = 0ull;
    __syncthreads();
    sort512(buf);

    if (tid < TOPK) {
        unsigned long long k = buf[tid];
        unsigned bits = (unsigned)(k >> 32);
        int n = (int)(~(unsigned)k);
        top_s[row * TOPK + tid] = __uint_as_float(bits);
        top_b[row * TOPK + tid] = boxes[(size_t)b * NTOT + n];
    }
}

// -------------------------- K4: greedy NMS (wave per row) -----------------
__global__ __launch_bounds__(256) void k_nms(
    const float* __restrict__ top_s, const float4* __restrict__ top_b,
    float* __restrict__ cand) {
    const int lane = threadIdx.x & 63;
    const int row  = blockIdx.x * 4 + (threadIdx.x >> 6);
    const float4* bb = top_b + (size_t)row * TOPK;
    const float*  ss = top_s + (size_t)row * TOPK;

    const int j0 = lane, j1 = lane + 64;
    const bool v1 = (j1 < TOPK);
    float4 B0 = bb[j0];
    float  s0 = ss[j0];
    float4 B1 = v1 ? bb[j1] : make_float4(0.f, 0.f, 0.f, 0.f);
    float  s1 = v1 ? ss[j1] : -1.0f;
    float ar0 = fmaxf(B0.z - B0.x, 0.f) * fmaxf(B0.w - B0.y, 0.f);
    float ar1 = fmaxf(B1.z - B1.x, 0.f) * fmaxf(B1.w - B1.y, 0.f);
    int sup0 = 0, sup1 = 0;

    for (int i = 0; i < TOPK; ++i) {
        const int src = i & 63;
        const bool hi = (i >= 64);
        float yi1 = __shfl(hi ? B1.x : B0.x, src, 64);
        float xi1 = __shfl(hi ? B1.y : B0.y, src, 64);
        float yi2 = __shfl(hi ? B1.z : B0.z, src, 64);
        float xi2 = __shfl(hi ? B1.w : B0.w, src, 64);
        float si  = __shfl(hi ? s1   : s0,   src, 64);
        int  supi = __shfl(hi ? sup1 : sup0, src, 64);
        bool keep_i = (si >= SCORE_THR) && (supi == 0);
        if (keep_i) {
            float ari = fmaxf(yi2 - yi1, 0.f) * fmaxf(xi2 - xi1, 0.f);
            if (j0 > i) {
                float ty1 = fmaxf(yi1, B0.x), tx1 = fmaxf(xi1, B0.y);
                float ty2 = fminf(yi2, B0.z), tx2 = fminf(xi2, B0.w);
                float inter = fmaxf(ty2 - ty1, 0.f) * fmaxf(tx2 - tx1, 0.f);
                float iou = inter / (ari + ar0 - inter + 1e-9f);
                if (iou > NMS_THR) sup0 = 1;
            }
            if (v1 && j1 > i) {
                float ty1 = fmaxf(yi1, B1.x), tx1 = fmaxf(xi1, B1.y);
                float ty2 = fminf(yi2, B1.z), tx2 = fminf(xi2, B1.w);
                float inter = fmaxf(ty2 - ty1, 0.f) * fmaxf(tx2 - tx1, 0.f);
                float iou = inter / (ari + ar1 - inter + 1e-9f);
                if (iou > NMS_THR) sup1 = 1;
            }
        }
    }
    cand[(size_t)row * TOPK + j0] = (s0 >= SCORE_THR && sup0 == 0) ? s0 : -1.0f;
    if (v1)
        cand[(size_t)row * TOPK + j1] = (s1 >= SCORE_THR && sup1 == 0) ? s1 : -1.0f;
}

// -------------------------- K5: per-image top-100 -------------------------
__global__ __launch_bounds__(256) void k_final(
    const float* __restrict__ cand, const float4* __restrict__ top_b,
    float* __restrict__ out) {
    __shared__ float cs[8000];                     // 32 KB
    __shared__ unsigned int hist[4096];            // 16 KB
    __shared__ unsigned long long buf[512];
    __shared__ unsigned int suf[256];
    __shared__ unsigned int sh_kp, sh_p1, sh_above1, sh_p2, sh_above2, sh_cnt;

    const int tid = threadIdx.x, b = blockIdx.x;
    if (tid == 0) { sh_kp = 0; sh_cnt = 0; }
    for (int i = tid; i < 4096; i += 256) hist[i] = 0;
    __syncthreads();

    unsigned lk = 0;
    for (int i = tid; i < 8000; i += 256) {
        float v = cand[b * 8000 + i];
        cs[i] = v;
        if (v > -0.5f) lk++;
    }
    atomicAdd(&sh_kp, lk);
    __syncthreads();
    unsigned Kp = sh_kp;

    if (Kp >= TOPK) {
        for (int i = tid; i < 8000; i += 256)
            if (cs[i] > -0.5f) atomicAdd(&hist[__float_as_uint(cs[i]) >> 19], 1u);
        __syncthreads();
        find_pivot(hist, 2048, TOPK, suf, &sh_p1, &sh_above1);
        unsigned p1 = sh_p1, above1 = sh_above1;
        for (int i = tid; i < 4096; i += 256) hist[i] = 0;
        __syncthreads();
        for (int i = tid; i < 8000; i += 256) {
            float v = cs[i];
            if (v > -0.5f) {
                unsigned bits = __float_as_uint(v);
                if ((bits >> 19) == p1) atomicAdd(&hist[(bits >> 7) & 0xFFFu], 1u);
            }
        }
        __syncthreads();
        find_pivot(hist, 4096, TOPK - above1, suf, &sh_p2, &sh_above2);
        unsigned p2 = sh_p2;
        for (int i = tid; i < 8000; i += 256) {
            float v = cs[i];
            if (v > -0.5f) {
                unsigned bits = __float_as_uint(v);
                unsigned b1 = bits >> 19;
                if (b1 > p1 || (b1 == p1 && ((bits >> 7) & 0xFFFu) >= p2)) {
                    unsigned slot = atomicAdd(&sh_cnt, 1u);
                    if (slot < 512)
                        buf[slot] = (((unsigned long long)bits) << 32) | (unsigned)(~i);
                }
            }
        }
        __syncthreads();
        unsigned M = sh_cnt; if (M > 512) M = 512;
        for (int i = tid; i < 512; i += 256) if ((unsigned)i >= M) buf[i] = 0ull;
    } else {
        for (int i = tid; i < 512; i += 256) buf[i] = 0ull;
        __syncthreads();
        for (int i = tid; i < 8000; i += 256) {
            float v = cs[i];
            if (v > -0.5f) {
                unsigned slot = atomicAdd(&sh_cnt, 1u);
                buf[slot] = (((unsigned long long)__float_as_uint(v)) << 32) | (unsigned)(~i);
            }
        }
        __syncthreads();
        if (tid == 0) {
            unsigned need = TOPK - Kp, got = 0;
            for (int i = 0; i < 8000 && got < need; ++i)
                if (cs[i] <= -0.5f) { buf[Kp + got] = (unsigned)(~i); got++; }
        }
    }
    __syncthreads();
    sort512(buf);

    if (tid < TOPK) {
        unsigned long long k = buf[tid];
        int i = (int)(~(unsigned)k);
        int c = i / TOPK; int kk = i - c * TOPK;
        float4 bb = top_b[((size_t)b * NCLS + c) * TOPK + kk];
        int base = (b * TOPK + tid) * 6;
        out[base + 0] = bb.x; out[base + 1] = bb.y;
        out[base + 2] = bb.z; out[base + 3] = bb.w;
        out[base + 4] = cs[i]; out[base + 5] = (float)c;
    }
}

// ---------------------------------------------------------------------------
extern "C" void kernel_launch(void* const* d_in, const int* in_sizes, int n_in,
                              void* d_out, int out_size, void* d_ws, size_t ws_size,
                              hipStream_t stream) {
    (void)n_in; (void)out_size; (void)ws_size;
    const float* f0      = (const float*)d_in[0];
    const float* f1      = (const float*)d_in[1];
    const float* f2      = (const float*)d_in[2];
    const float* anchors = (const float*)d_in[3];
    const float* imshape = (const float*)d_in[4];
    const int B = in_sizes[0] / (255 * 19 * 19);

    char* ws = (char*)d_ws;
    size_t o = 0;
    unsigned short* keybuf = (unsigned short*)(ws + o);
    o += (size_t)B * NCLS * KPAD * sizeof(unsigned short);   // 58.2 MB
    float4* boxes  = (float4*)(ws + o); o += (size_t)B * NTOT * sizeof(float4);
    float*  conf_p = (float*)(ws + o);  o += (size_t)B * NTOT * sizeof(float);
    float*  top_s  = (float*)(ws + o);  o += (size_t)B * NCLS * TOPK * sizeof(float);
    float4* top_b  = (float4*)(ws + o); o += (size_t)B * NCLS * TOPK * sizeof(float4);
    float*  cand   = (float*)(ws + o);  o += (size_t)B * NCLS * TOPK * sizeof(float);
    float*  out    = (float*)d_out;

    const int total = B * NTOT;
    k_decode<<<(total + 255) / 256, 256, 0, stream>>>(f0, f1, f2, anchors, imshape,
                                                      boxes, conf_p, total);
    k_score<<<B * 93, 256, 0, stream>>>(f0, f1, f2, conf_p, keybuf);
    k_topk<<<B * NCLS, 256, 0, stream>>>(f0, f1, f2, conf_p, keybuf, boxes,
                                         top_s, top_b);
    k_nms<<<(B * NCLS) / 4, 256, 0, stream>>>(top_s, top_b, cand);
    k_final<<<B, 256, 0, stream>>>(cand, top_b, out);
}